// Round 5
// baseline (536.294 us; speedup 1.0000x reference)
//
#include <hip/hip_runtime.h>

// ---------------------------------------------------------------------------
// LinearAttention (Taylor feature map), MI355X/gfx950.
// Inputs: FLOAT32 (runtime-probed; bf16 copies in ws). Outputs: FLOAT32
// [out (4,2048,1024) | kv_state (4,16,1,64,273)] -> 9,506,816 f32 elements.
//
// qf.kf = 1 + (q.k)/4 + (q.k)^2/32 -> attention needs only S=QK^T.
//
// Pipeline: cvt(f32->bf16) -> gemm_nt<0> (QKV proj, MFMA bf16) ->
//   attn (y unnormalized [b,h,l,64] bf16) -> rms (yn [b,l,1024] bf16) ->
//   kv_acc/kv_fin (f32) -> gemm_nt<1> (out = yn @ Wo^T, f32 stores)
// ---------------------------------------------------------------------------

typedef unsigned short u16;
typedef __attribute__((ext_vector_type(4))) float f32x4;
typedef __attribute__((ext_vector_type(8))) short s16x8;

__device__ __forceinline__ float bf2f(u16 u) {
    union { unsigned int i; float f; } x; x.i = ((unsigned int)u) << 16; return x.f;
}
__device__ __forceinline__ u16 f2bf(float f) {
    union { float f; unsigned int u; } x; x.f = f;
    unsigned int r = x.u + 0x7FFFu + ((x.u >> 16) & 1u);
    return (u16)(r >> 16);
}

// ---------------- input dtype probe + convert -------------------------------
__global__ void detect_kernel(const unsigned int* __restrict__ H, int* __restrict__ flag)
{
    const int lane = threadIdx.x;
    int cnt = 0;
#pragma unroll
    for (int i = 0; i < 16; ++i) {
        const unsigned int wrd = H[lane * 16 + i];
        const int e = (int)((wrd >> 7) & 0xFFu);
        if (e >= 85 && e <= 170) ++cnt;
    }
    cnt += __shfl_xor(cnt, 1);  cnt += __shfl_xor(cnt, 2);
    cnt += __shfl_xor(cnt, 4);  cnt += __shfl_xor(cnt, 8);
    cnt += __shfl_xor(cnt, 16); cnt += __shfl_xor(cnt, 32);
    if (lane == 0) *flag = (cnt < 700) ? 1 : 0;    // 1 = inputs are f32
}

__global__ __launch_bounds__(256)
void cvt_kernel(const void* __restrict__ src, u16* __restrict__ dst, int n,
                const int* __restrict__ flag)
{
    const int i = blockIdx.x * 256 + threadIdx.x;
    if (i >= n) return;
    if (*flag) dst[i] = f2bf(((const float*)src)[i]);
    else       dst[i] = ((const u16*)src)[i];
}

// ---------------- GEMM: C = A(8192,1024) . B(N,1024)^T, bf16 in, f32 acc ----
// MODE 0: fused QKV (N=1536), bf16 head-interleaved outputs q/k/v.
// MODE 1: N=1024, FLOAT32 row-major output Of.
template<int MODE>
__global__ __launch_bounds__(256)
void gemm_nt(const u16* __restrict__ A,
             const u16* __restrict__ Bq, const u16* __restrict__ Bk,
             const u16* __restrict__ Bv,
             u16* __restrict__ Oq, u16* __restrict__ Ok,
             u16* __restrict__ Ov, float* __restrict__ Of)
{
    __shared__ __attribute__((aligned(16))) u16 As[128][40];
    __shared__ __attribute__((aligned(16))) u16 Bs[128][40];
    const int t = threadIdx.x;
    const int lane = t & 63, w = t >> 6;
    const int c = lane & 15, qd = lane >> 4;
    const int wm = (w >> 1) * 64, wn = (w & 1) * 64;
    const int rm = blockIdx.y * 128;
    const int cb = blockIdx.x * 128;

    const u16* Bsrc; int wrow0;
    if (MODE == 0) {
        if (cb < 256)      { Bsrc = Bq; wrow0 = cb; }
        else if (cb < 512) { Bsrc = Bk; wrow0 = cb - 256; }
        else               { Bsrc = Bv; wrow0 = cb - 512; }
    } else { Bsrc = Bq; wrow0 = cb; }

    f32x4 acc[4][4];
#pragma unroll
    for (int i = 0; i < 4; ++i)
#pragma unroll
        for (int j = 0; j < 4; ++j) acc[i][j] = (f32x4){0.f, 0.f, 0.f, 0.f};

    const int r0 = t >> 2, s0 = t & 3;
    const u16* Ap = A    + (size_t)(rm    + r0) * 1024 + s0 * 8;
    const u16* Bp = Bsrc + (size_t)(wrow0 + r0) * 1024 + s0 * 8;

    for (int kt = 0; kt < 32; ++kt) {
        const int k0 = kt * 32;
        uint4 a0 = *(const uint4*)(Ap + k0);
        uint4 a1 = *(const uint4*)(Ap + 64 * 1024 + k0);
        uint4 b0 = *(const uint4*)(Bp + k0);
        uint4 b1 = *(const uint4*)(Bp + 64 * 1024 + k0);
        __syncthreads();
        *(uint4*)&As[r0][s0 * 8]      = a0;
        *(uint4*)&As[r0 + 64][s0 * 8] = a1;
        *(uint4*)&Bs[r0][s0 * 8]      = b0;
        *(uint4*)&Bs[r0 + 64][s0 * 8] = b1;
        __syncthreads();
        s16x8 af[4], bfr[4];
#pragma unroll
        for (int mt = 0; mt < 4; ++mt) af[mt]  = *(const s16x8*)&As[wm + mt * 16 + c][qd * 8];
#pragma unroll
        for (int nt = 0; nt < 4; ++nt) bfr[nt] = *(const s16x8*)&Bs[wn + nt * 16 + c][qd * 8];
#pragma unroll
        for (int mt = 0; mt < 4; ++mt)
#pragma unroll
            for (int nt = 0; nt < 4; ++nt)
                acc[mt][nt] = __builtin_amdgcn_mfma_f32_16x16x32_bf16(af[mt], bfr[nt], acc[mt][nt], 0, 0, 0);
    }

#pragma unroll
    for (int mt = 0; mt < 4; ++mt) {
#pragma unroll
        for (int nt = 0; nt < 4; ++nt) {
            const int gc = cb + wn + nt * 16 + c;
#pragma unroll
            for (int r = 0; r < 4; ++r) {
                const int row = rm + wm + mt * 16 + qd * 4 + r;
                if (MODE == 1) {
                    Of[(size_t)row * 1024 + gc] = acc[mt][nt][r];   // FLOAT32 out
                } else {
                    const u16 hv = f2bf(acc[mt][nt][r]);
                    const int b_ = row >> 11, l_ = row & 2047;
                    if (gc < 512) {
                        const int cc = gc & 255;
                        const int h = cc >> 4, idx = cc & 15;
                        u16* dst = (gc < 256) ? Oq : Ok;
                        dst[(size_t)((b_ * 16 + h) * 2048 + l_) * 16 + idx] = hv;
                    } else {
                        const int cc = gc - 512;
                        const int h = cc >> 6, idx = cc & 63;
                        Ov[(size_t)((b_ * 16 + h) * 2048 + l_) * 64 + idx] = hv;
                    }
                }
            }
        }
    }
}

// ---------------- causal phi-attention, UNNORMALIZED y ----------------------
__global__ __launch_bounds__(256)
void attn_kernel(const u16* __restrict__ Qg, const u16* __restrict__ Kg,
                 const u16* __restrict__ Vg, u16* __restrict__ Yg)
{
    __shared__ __attribute__((aligned(16))) u16 Qs[128][16];
    __shared__ __attribute__((aligned(16))) u16 Ks[128][16];
    __shared__ __attribute__((aligned(16))) u16 Vs[64][136];   // V^T chunk [f][n]
    __shared__ __attribute__((aligned(16))) u16 Ps[128][136];  // phi(S) bf16
    const int t = threadIdx.x, lane = t & 63, w = t >> 6;
    const int c = lane & 15, qd = lane >> 4;
    const int bh = blockIdx.y, qc = blockIdx.x;
    const int q0 = qc * 128;
    const u16* Qh = Qg + (size_t)bh * (2048 * 16);
    const u16* Kh = Kg + (size_t)bh * (2048 * 16);
    const u16* Vh = Vg + (size_t)bh * (2048 * 64);

    {
        const int row = t >> 1, half = t & 1;
        uint4 qv = *(const uint4*)(Qh + (size_t)(q0 + row) * 16 + half * 8);
        *(uint4*)&Qs[row][half * 8] = qv;
    }
    __syncthreads();
    s16x8 qa[2];
#pragma unroll
    for (int mt = 0; mt < 2; ++mt) {
        s16x8 tmp = {0,0,0,0,0,0,0,0};
        if (qd < 2) tmp = *(const s16x8*)&Qs[w * 32 + mt * 16 + c][qd * 8];
        qa[mt] = tmp;
    }

    f32x4 yt[2][4];
#pragma unroll
    for (int mt = 0; mt < 2; ++mt)
#pragma unroll
        for (int ft = 0; ft < 4; ++ft) yt[mt][ft] = (f32x4){0.f,0.f,0.f,0.f};
    const f32x4 zacc = {0.f, 0.f, 0.f, 0.f};

    for (int kc = 0; kc <= qc; ++kc) {
        const int n0 = kc * 128;
        __syncthreads();
        {
            const int row = t >> 1, half = t & 1;
            uint4 kv = *(const uint4*)(Kh + (size_t)(n0 + row) * 16 + half * 8);
            *(uint4*)&Ks[row][half * 8] = kv;
        }
#pragma unroll
        for (int i = 0; i < 4; ++i) {
            const int lin = i * 256 + t;
            const int nl = lin >> 3, f8 = (lin & 7) * 8;
            const u16* vp = Vh + (size_t)(n0 + nl) * 64 + f8;
            uint4 vv = *(const uint4*)vp;
            const u16* ve = (const u16*)&vv;
#pragma unroll
            for (int e = 0; e < 8; ++e) Vs[f8 + e][nl] = ve[e];
        }
        __syncthreads();

        f32x4 s[2][8];
#pragma unroll
        for (int nt = 0; nt < 8; ++nt) {
            s16x8 kb = {0,0,0,0,0,0,0,0};
            if (qd < 2) kb = *(const s16x8*)&Ks[nt * 16 + c][qd * 8];
#pragma unroll
            for (int mt = 0; mt < 2; ++mt)
                s[mt][nt] = __builtin_amdgcn_mfma_f32_16x16x32_bf16(qa[mt], kb, zacc, 0, 0, 0);
        }
        const bool diag = (kc == qc);
#pragma unroll
        for (int mt = 0; mt < 2; ++mt)
#pragma unroll
            for (int nt = 0; nt < 8; ++nt)
#pragma unroll
                for (int r = 0; r < 4; ++r) {
                    const float sv = s[mt][nt][r];
                    float p = 1.f + 0.25f * sv + 0.03125f * sv * sv;
                    const int row = w * 32 + mt * 16 + qd * 4 + r;
                    const int col = nt * 16 + c;
                    if (diag && col > row) p = 0.f;
                    Ps[row][col] = f2bf(p);
                }
        __syncthreads();

#pragma unroll
        for (int kt = 0; kt < 4; ++kt) {
            s16x8 pa[2], vb[4];
#pragma unroll
            for (int mt = 0; mt < 2; ++mt)
                pa[mt] = *(const s16x8*)&Ps[w * 32 + mt * 16 + c][kt * 32 + qd * 8];
#pragma unroll
            for (int ft = 0; ft < 4; ++ft)
                vb[ft] = *(const s16x8*)&Vs[ft * 16 + c][kt * 32 + qd * 8];
#pragma unroll
            for (int mt = 0; mt < 2; ++mt)
#pragma unroll
                for (int ft = 0; ft < 4; ++ft)
                    yt[mt][ft] = __builtin_amdgcn_mfma_f32_16x16x32_bf16(pa[mt], vb[ft], yt[mt][ft], 0, 0, 0);
        }
    }

#pragma unroll
    for (int mt = 0; mt < 2; ++mt) {
#pragma unroll
        for (int r = 0; r < 4; ++r) {
            const int i = q0 + w * 32 + mt * 16 + qd * 4 + r;
            u16* dst = Yg + ((size_t)bh * 2048 + i) * 64;
#pragma unroll
            for (int ft = 0; ft < 4; ++ft)
                dst[ft * 16 + c] = f2bf(yt[mt][ft][r]);
        }
    }
}

// ---------------- standalone RMSNorm: y [b,h,l,64] -> yn [b,l,1024] ---------
__global__ __launch_bounds__(256)
void rms_kernel(const u16* __restrict__ Yg, const u16* __restrict__ gw,
                u16* __restrict__ Yn)
{
    const int t = threadIdx.x, lane = t & 63, wv = t >> 6;
    const int row = blockIdx.x * 4 + wv;           // row = (b*16+h)*2048 + l
    const float v = bf2f(Yg[(size_t)row * 64 + lane]);
    float ss = v * v;
    ss += __shfl_xor(ss, 1);  ss += __shfl_xor(ss, 2);
    ss += __shfl_xor(ss, 4);  ss += __shfl_xor(ss, 8);
    ss += __shfl_xor(ss, 16); ss += __shfl_xor(ss, 32);
    const float rms = rsqrtf(ss * (1.0f / 64.0f) + 1e-5f);
    const int bh = row >> 11, l = row & 2047;
    const int b_ = bh >> 4, h_ = bh & 15;
    Yn[((size_t)(b_ * 2048 + l)) * 1024 + h_ * 64 + lane] =
        f2bf(v * rms * bf2f(gw[lane]));
}

// ---------------- kv_state = sum_n kf(n) v(n)^T -----------------------------
__global__ __launch_bounds__(320)
void kv_acc_kernel(const u16* __restrict__ Kg, const u16* __restrict__ Vg,
                   float* __restrict__ kvacc)
{
    __shared__ __attribute__((aligned(16))) float kS[128][17];
    __shared__ __attribute__((aligned(16))) float vS[128][64];
    const int t = threadIdx.x;
    const int ns = blockIdx.x, bh = blockIdx.y;
    const u16* Kh = Kg + (size_t)bh * 2048 * 16;
    const u16* Vh = Vg + (size_t)bh * 2048 * 64;
    int i2, j2; float sc;
    if (t == 0 || t >= 273) { i2 = 16; j2 = 16; sc = (t == 0) ? 1.f : 0.f; }
    else if (t < 17)        { i2 = t - 1; j2 = 16; sc = 0.5f; }
    else                    { i2 = (t - 17) >> 4; j2 = (t - 17) & 15; sc = 0.17677669529663687f; }
    float acc[64];
#pragma unroll
    for (int f = 0; f < 64; ++f) acc[f] = 0.f;
    for (int ch = 0; ch < 2; ++ch) {
        const int n0 = ns * 256 + ch * 128;
        __syncthreads();
        for (int idx = t; idx < 128 * 16; idx += 320)
            kS[idx >> 4][idx & 15] = bf2f(Kh[(size_t)(n0 + (idx >> 4)) * 16 + (idx & 15)]);
        for (int idx = t; idx < 128; idx += 320) kS[idx][16] = 1.f;
        for (int idx = t; idx < 128 * 64; idx += 320)
            vS[idx >> 6][idx & 63] = bf2f(Vh[(size_t)(n0 + (idx >> 6)) * 64 + (idx & 63)]);
        __syncthreads();
        for (int n = 0; n < 128; ++n) {
            const float coef = kS[n][i2] * kS[n][j2] * sc;
            const float4* vrow = (const float4*)&vS[n][0];
#pragma unroll
            for (int f4 = 0; f4 < 16; ++f4) {
                const float4 vv = vrow[f4];
                acc[f4 * 4 + 0] += coef * vv.x;
                acc[f4 * 4 + 1] += coef * vv.y;
                acc[f4 * 4 + 2] += coef * vv.z;
                acc[f4 * 4 + 3] += coef * vv.w;
            }
        }
    }
    if (t < 273) {
        float* dst = kvacc + (size_t)bh * 17472 + t;   // [f*273 + dd]
#pragma unroll 8
        for (int f = 0; f < 64; ++f) atomicAdd(dst + f * 273, acc[f]);
    }
}

__global__ __launch_bounds__(256)
void kv_fin_kernel(const float* __restrict__ kvacc, float* __restrict__ o)
{
    const int i = blockIdx.x * 256 + threadIdx.x;
    if (i < 64 * 64 * 273) o[i] = kvacc[i];      // FLOAT32 out
}

// ---------------------------------------------------------------------------
extern "C" void kernel_launch(void* const* d_in, const int* in_sizes, int n_in,
                              void* d_out, int out_size, void* d_ws, size_t ws_size,
                              hipStream_t stream)
{
    const void* H  = d_in[0];
    const void* Wq = d_in[1];
    const void* Wk = d_in[2];
    const void* Wv = d_in[3];
    const void* Wo = d_in[4];
    const void* gw = d_in[5];
    float* outf = (float*)d_out;

    char* ws = (char*)d_ws;
    const size_t M = 1 << 20;
    u16*   Hb    = (u16*)(ws);                          // 16 MiB (reused as yn)
    u16*   Wqb   = (u16*)(ws + 16 * M);
    u16*   Wkb   = (u16*)(ws + 16 * M + 512 * 1024);
    u16*   Wvb   = (u16*)(ws + 17 * M);
    u16*   Wob   = (u16*)(ws + 19 * M);
    u16*   gwb   = (u16*)(ws + 21 * M);
    int*   flag  = (int*)(ws + 21 * M + 4096);
    u16*   q     = (u16*)(ws + 22 * M);                 // 4 MiB
    u16*   k     = (u16*)(ws + 26 * M);                 // 4 MiB
    u16*   v     = (u16*)(ws + 30 * M);                 // 16 MiB [b,h,l,64]
    u16*   y     = (u16*)(ws + 46 * M);                 // 16 MiB [b,h,l,64]
    float* kvacc = (float*)(ws + 62 * M);               // 4.26 MiB
    u16*   yn    = Hb;                                  // reuse after gemm0

    detect_kernel<<<1, 64, 0, stream>>>((const unsigned int*)H, flag);
    cvt_kernel<<<(in_sizes[0] + 255) / 256, 256, 0, stream>>>(H,  Hb,  in_sizes[0], flag);
    cvt_kernel<<<(in_sizes[1] + 255) / 256, 256, 0, stream>>>(Wq, Wqb, in_sizes[1], flag);
    cvt_kernel<<<(in_sizes[2] + 255) / 256, 256, 0, stream>>>(Wk, Wkb, in_sizes[2], flag);
    cvt_kernel<<<(in_sizes[3] + 255) / 256, 256, 0, stream>>>(Wv, Wvb, in_sizes[3], flag);
    cvt_kernel<<<(in_sizes[4] + 255) / 256, 256, 0, stream>>>(Wo, Wob, in_sizes[4], flag);
    cvt_kernel<<<1, 256, 0, stream>>>(gw, gwb, in_sizes[5], flag);

    hipMemsetAsync(kvacc, 0, (size_t)64 * 64 * 273 * sizeof(float), stream);
    gemm_nt<0><<<dim3(12, 64), 256, 0, stream>>>(Hb, Wqb, Wkb, Wvb, q, k, v, nullptr);
    attn_kernel<<<dim3(16, 64), 256, 0, stream>>>(q, k, v, y);
    rms_kernel<<<32768, 256, 0, stream>>>(y, gwb, yn);
    kv_acc_kernel<<<dim3(8, 64), 320, 0, stream>>>(k, v, kvacc);
    kv_fin_kernel<<<4368, 256, 0, stream>>>(kvacc, outf + (size_t)8388608);
    gemm_nt<1><<<dim3(8, 64), 256, 0, stream>>>(yn, Wob, nullptr, nullptr,
                                                nullptr, nullptr, nullptr, outf);
}

// Round 6
// 428.476 us; speedup vs baseline: 1.2516x; 1.2516x over previous
//
#include <hip/hip_runtime.h>

// ---------------------------------------------------------------------------
// LinearAttention (Taylor feature map), MI355X/gfx950.
// Inputs: FLOAT32 (runtime-probed; bf16 copies in ws). Outputs: FLOAT32
// [out (4,2048,1024) | kv_state (4,16,1,64,273)].
//
// qf.kf = 1 + (q.k)/4 + (q.k)^2/32 -> attention needs only S=QK^T.
// kv_state is a GEMM: KV[f,dd] = sum_n V^T[f,n] KF[n,dd] -> MFMA (r6 change).
// ---------------------------------------------------------------------------

typedef unsigned short u16;
typedef __attribute__((ext_vector_type(4))) float f32x4;
typedef __attribute__((ext_vector_type(8))) short s16x8;

__device__ __forceinline__ float bf2f(u16 u) {
    union { unsigned int i; float f; } x; x.i = ((unsigned int)u) << 16; return x.f;
}
__device__ __forceinline__ u16 f2bf(float f) {
    union { float f; unsigned int u; } x; x.f = f;
    unsigned int r = x.u + 0x7FFFu + ((x.u >> 16) & 1u);
    return (u16)(r >> 16);
}

// ---------------- input dtype probe + convert -------------------------------
__global__ void detect_kernel(const unsigned int* __restrict__ H, int* __restrict__ flag)
{
    const int lane = threadIdx.x;
    int cnt = 0;
#pragma unroll
    for (int i = 0; i < 16; ++i) {
        const unsigned int wrd = H[lane * 16 + i];
        const int e = (int)((wrd >> 7) & 0xFFu);
        if (e >= 85 && e <= 170) ++cnt;
    }
    cnt += __shfl_xor(cnt, 1);  cnt += __shfl_xor(cnt, 2);
    cnt += __shfl_xor(cnt, 4);  cnt += __shfl_xor(cnt, 8);
    cnt += __shfl_xor(cnt, 16); cnt += __shfl_xor(cnt, 32);
    if (lane == 0) *flag = (cnt < 700) ? 1 : 0;    // 1 = inputs are f32
}

__global__ __launch_bounds__(256)
void cvt_kernel(const void* __restrict__ src, u16* __restrict__ dst, int n,
                const int* __restrict__ flag)
{
    const int i = blockIdx.x * 256 + threadIdx.x;
    if (i >= n) return;
    if (*flag) dst[i] = f2bf(((const float*)src)[i]);
    else       dst[i] = ((const u16*)src)[i];
}

// ---------------- GEMM: C = A(8192,1024) . B(N,1024)^T, bf16 in, f32 acc ----
template<int MODE>
__global__ __launch_bounds__(256)
void gemm_nt(const u16* __restrict__ A,
             const u16* __restrict__ Bq, const u16* __restrict__ Bk,
             const u16* __restrict__ Bv,
             u16* __restrict__ Oq, u16* __restrict__ Ok,
             u16* __restrict__ Ov, float* __restrict__ Of)
{
    __shared__ __attribute__((aligned(16))) u16 As[128][40];
    __shared__ __attribute__((aligned(16))) u16 Bs[128][40];
    const int t = threadIdx.x;
    const int lane = t & 63, w = t >> 6;
    const int c = lane & 15, qd = lane >> 4;
    const int wm = (w >> 1) * 64, wn = (w & 1) * 64;
    const int rm = blockIdx.y * 128;
    const int cb = blockIdx.x * 128;

    const u16* Bsrc; int wrow0;
    if (MODE == 0) {
        if (cb < 256)      { Bsrc = Bq; wrow0 = cb; }
        else if (cb < 512) { Bsrc = Bk; wrow0 = cb - 256; }
        else               { Bsrc = Bv; wrow0 = cb - 512; }
    } else { Bsrc = Bq; wrow0 = cb; }

    f32x4 acc[4][4];
#pragma unroll
    for (int i = 0; i < 4; ++i)
#pragma unroll
        for (int j = 0; j < 4; ++j) acc[i][j] = (f32x4){0.f, 0.f, 0.f, 0.f};

    const int r0 = t >> 2, s0 = t & 3;
    const u16* Ap = A    + (size_t)(rm    + r0) * 1024 + s0 * 8;
    const u16* Bp = Bsrc + (size_t)(wrow0 + r0) * 1024 + s0 * 8;

    for (int kt = 0; kt < 32; ++kt) {
        const int k0 = kt * 32;
        uint4 a0 = *(const uint4*)(Ap + k0);
        uint4 a1 = *(const uint4*)(Ap + 64 * 1024 + k0);
        uint4 b0 = *(const uint4*)(Bp + k0);
        uint4 b1 = *(const uint4*)(Bp + 64 * 1024 + k0);
        __syncthreads();
        *(uint4*)&As[r0][s0 * 8]      = a0;
        *(uint4*)&As[r0 + 64][s0 * 8] = a1;
        *(uint4*)&Bs[r0][s0 * 8]      = b0;
        *(uint4*)&Bs[r0 + 64][s0 * 8] = b1;
        __syncthreads();
        s16x8 af[4], bfr[4];
#pragma unroll
        for (int mt = 0; mt < 4; ++mt) af[mt]  = *(const s16x8*)&As[wm + mt * 16 + c][qd * 8];
#pragma unroll
        for (int nt = 0; nt < 4; ++nt) bfr[nt] = *(const s16x8*)&Bs[wn + nt * 16 + c][qd * 8];
#pragma unroll
        for (int mt = 0; mt < 4; ++mt)
#pragma unroll
            for (int nt = 0; nt < 4; ++nt)
                acc[mt][nt] = __builtin_amdgcn_mfma_f32_16x16x32_bf16(af[mt], bfr[nt], acc[mt][nt], 0, 0, 0);
    }

#pragma unroll
    for (int mt = 0; mt < 4; ++mt) {
#pragma unroll
        for (int nt = 0; nt < 4; ++nt) {
            const int gc = cb + wn + nt * 16 + c;
#pragma unroll
            for (int r = 0; r < 4; ++r) {
                const int row = rm + wm + mt * 16 + qd * 4 + r;
                if (MODE == 1) {
                    Of[(size_t)row * 1024 + gc] = acc[mt][nt][r];   // FLOAT32 out
                } else {
                    const u16 hv = f2bf(acc[mt][nt][r]);
                    const int b_ = row >> 11, l_ = row & 2047;
                    if (gc < 512) {
                        const int cc = gc & 255;
                        const int h = cc >> 4, idx = cc & 15;
                        u16* dst = (gc < 256) ? Oq : Ok;
                        dst[(size_t)((b_ * 16 + h) * 2048 + l_) * 16 + idx] = hv;
                    } else {
                        const int cc = gc - 512;
                        const int h = cc >> 6, idx = cc & 63;
                        Ov[(size_t)((b_ * 16 + h) * 2048 + l_) * 64 + idx] = hv;
                    }
                }
            }
        }
    }
}

// ---------------- causal phi-attention, UNNORMALIZED y ----------------------
__global__ __launch_bounds__(256)
void attn_kernel(const u16* __restrict__ Qg, const u16* __restrict__ Kg,
                 const u16* __restrict__ Vg, u16* __restrict__ Yg)
{
    __shared__ __attribute__((aligned(16))) u16 Qs[128][16];
    __shared__ __attribute__((aligned(16))) u16 Ks[128][16];
    __shared__ __attribute__((aligned(16))) u16 Vs[64][136];   // V^T chunk [f][n]
    __shared__ __attribute__((aligned(16))) u16 Ps[128][136];  // phi(S) bf16
    const int t = threadIdx.x, lane = t & 63, w = t >> 6;
    const int c = lane & 15, qd = lane >> 4;
    const int bh = blockIdx.y, qc = blockIdx.x;
    const int q0 = qc * 128;
    const u16* Qh = Qg + (size_t)bh * (2048 * 16);
    const u16* Kh = Kg + (size_t)bh * (2048 * 16);
    const u16* Vh = Vg + (size_t)bh * (2048 * 64);

    {
        const int row = t >> 1, half = t & 1;
        uint4 qv = *(const uint4*)(Qh + (size_t)(q0 + row) * 16 + half * 8);
        *(uint4*)&Qs[row][half * 8] = qv;
    }
    __syncthreads();
    s16x8 qa[2];
#pragma unroll
    for (int mt = 0; mt < 2; ++mt) {
        s16x8 tmp = {0,0,0,0,0,0,0,0};
        if (qd < 2) tmp = *(const s16x8*)&Qs[w * 32 + mt * 16 + c][qd * 8];
        qa[mt] = tmp;
    }

    f32x4 yt[2][4];
#pragma unroll
    for (int mt = 0; mt < 2; ++mt)
#pragma unroll
        for (int ft = 0; ft < 4; ++ft) yt[mt][ft] = (f32x4){0.f,0.f,0.f,0.f};
    const f32x4 zacc = {0.f, 0.f, 0.f, 0.f};

    for (int kc = 0; kc <= qc; ++kc) {
        const int n0 = kc * 128;
        __syncthreads();
        {
            const int row = t >> 1, half = t & 1;
            uint4 kv = *(const uint4*)(Kh + (size_t)(n0 + row) * 16 + half * 8);
            *(uint4*)&Ks[row][half * 8] = kv;
        }
#pragma unroll
        for (int i = 0; i < 4; ++i) {
            const int lin = i * 256 + t;
            const int nl = lin >> 3, f8 = (lin & 7) * 8;
            const u16* vp = Vh + (size_t)(n0 + nl) * 64 + f8;
            uint4 vv = *(const uint4*)vp;
            const u16* ve = (const u16*)&vv;
#pragma unroll
            for (int e = 0; e < 8; ++e) Vs[f8 + e][nl] = ve[e];
        }
        __syncthreads();

        f32x4 s[2][8];
#pragma unroll
        for (int nt = 0; nt < 8; ++nt) {
            s16x8 kb = {0,0,0,0,0,0,0,0};
            if (qd < 2) kb = *(const s16x8*)&Ks[nt * 16 + c][qd * 8];
#pragma unroll
            for (int mt = 0; mt < 2; ++mt)
                s[mt][nt] = __builtin_amdgcn_mfma_f32_16x16x32_bf16(qa[mt], kb, zacc, 0, 0, 0);
        }
        const bool diag = (kc == qc);
#pragma unroll
        for (int mt = 0; mt < 2; ++mt)
#pragma unroll
            for (int nt = 0; nt < 8; ++nt)
#pragma unroll
                for (int r = 0; r < 4; ++r) {
                    const float sv = s[mt][nt][r];
                    float p = 1.f + 0.25f * sv + 0.03125f * sv * sv;
                    const int row = w * 32 + mt * 16 + qd * 4 + r;
                    const int col = nt * 16 + c;
                    if (diag && col > row) p = 0.f;
                    Ps[row][col] = f2bf(p);
                }
        __syncthreads();

#pragma unroll
        for (int kt = 0; kt < 4; ++kt) {
            s16x8 pa[2], vb[4];
#pragma unroll
            for (int mt = 0; mt < 2; ++mt)
                pa[mt] = *(const s16x8*)&Ps[w * 32 + mt * 16 + c][kt * 32 + qd * 8];
#pragma unroll
            for (int ft = 0; ft < 4; ++ft)
                vb[ft] = *(const s16x8*)&Vs[ft * 16 + c][kt * 32 + qd * 8];
#pragma unroll
            for (int mt = 0; mt < 2; ++mt)
#pragma unroll
                for (int ft = 0; ft < 4; ++ft)
                    yt[mt][ft] = __builtin_amdgcn_mfma_f32_16x16x32_bf16(pa[mt], vb[ft], yt[mt][ft], 0, 0, 0);
        }
    }

#pragma unroll
    for (int mt = 0; mt < 2; ++mt) {
#pragma unroll
        for (int r = 0; r < 4; ++r) {
            const int i = q0 + w * 32 + mt * 16 + qd * 4 + r;
            u16* dst = Yg + ((size_t)bh * 2048 + i) * 64;
#pragma unroll
            for (int ft = 0; ft < 4; ++ft)
                dst[ft * 16 + c] = f2bf(yt[mt][ft][r]);
        }
    }
}

// ---------------- standalone RMSNorm: y [b,h,l,64] -> yn [b,l,1024] ---------
__global__ __launch_bounds__(256)
void rms_kernel(const u16* __restrict__ Yg, const u16* __restrict__ gw,
                u16* __restrict__ Yn)
{
    const int t = threadIdx.x, lane = t & 63, wv = t >> 6;
    const int row = blockIdx.x * 4 + wv;           // row = (b*16+h)*2048 + l
    const float v = bf2f(Yg[(size_t)row * 64 + lane]);
    float ss = v * v;
    ss += __shfl_xor(ss, 1);  ss += __shfl_xor(ss, 2);
    ss += __shfl_xor(ss, 4);  ss += __shfl_xor(ss, 8);
    ss += __shfl_xor(ss, 16); ss += __shfl_xor(ss, 32);
    const float rms = rsqrtf(ss * (1.0f / 64.0f) + 1e-5f);
    const int bh = row >> 11, l = row & 2047;
    const int b_ = bh >> 4, h_ = bh & 15;
    Yn[((size_t)(b_ * 2048 + l)) * 1024 + h_ * 64 + lane] =
        f2bf(v * rms * bf2f(gw[lane]));
}

// ---------------- kv_state as MFMA GEMM -------------------------------------
// KV[f,dd] = sum_n V^T[f,n] KF[n,dd].  Per block: bh = blockIdx.y,
// n-split ns = blockIdx.x (2 splits x 1024 n = 16 chunks of 64).
// LDS: kS/kT [64][20] f32 (k + pre-scaled k; cols 16..18 = specials),
//      KFs [288][72] bf16 in TRANSPOSED [dd][n] layout, Vs [64][72] = V^T.
// Wave w owns dd-tiles {w, w+4, w+8, w+12, w+16} (<18); 4 f-tiles each.
__global__ __launch_bounds__(256)
void kv_mfma_kernel(const u16* __restrict__ Kg, const u16* __restrict__ Vg,
                    float* __restrict__ kvpart)
{
    __shared__ __attribute__((aligned(16))) float kS[64][20];
    __shared__ __attribute__((aligned(16))) float kT[64][20];
    __shared__ __attribute__((aligned(16))) u16 KFs[288][72];
    __shared__ __attribute__((aligned(16))) u16 Vs[64][72];
    const int t = threadIdx.x, lane = t & 63, w = t >> 6;
    const int c = lane & 15, qd = lane >> 4;
    const int ns = blockIdx.x, bh = blockIdx.y;
    const u16* Kh = Kg + (size_t)bh * 2048 * 16;
    const u16* Vh = Vg + (size_t)bh * 2048 * 64;

    // this thread's feature indices (dd0 = t, dd1 = 256+t for t<32)
    int i2a, j2a, i2b = 18, j2b = 18;
    {
        const int dd = t;
        if (dd == 0)      { i2a = 16; j2a = 17; }
        else if (dd < 17) { i2a = dd - 1; j2a = 16; }
        else              { i2a = (dd - 17) >> 4; j2a = (dd - 17) & 15; }
        if (t < 32) {
            const int d2 = 256 + t;
            if (d2 < 273) { i2b = (d2 - 17) >> 4; j2b = (d2 - 17) & 15; }
            // else stays (18,18) -> 0
        }
    }

    f32x4 acc[4][5];
#pragma unroll
    for (int mt = 0; mt < 4; ++mt)
#pragma unroll
        for (int j = 0; j < 5; ++j) acc[mt][j] = (f32x4){0.f, 0.f, 0.f, 0.f};

    for (int ch = 0; ch < 16; ++ch) {
        const int n0 = ns * 1024 + ch * 64;
        __syncthreads();   // protect LDS from previous iteration's readers
        // stage K -> kS (f32) and kT (pre-scaled by 1/(4*sqrt2))
        if (t < 128) {
            const int row = t >> 1, half = t & 1;
            uint4 kv = *(const uint4*)(Kh + (size_t)(n0 + row) * 16 + half * 8);
            const u16* ke = (const u16*)&kv;
#pragma unroll
            for (int e = 0; e < 8; ++e) {
                const float f = bf2f(ke[e]);
                kS[row][half * 8 + e] = f;
                kT[row][half * 8 + e] = f * 0.17677669529663687f;
            }
        } else if (t < 192) {
            const int row = t - 128;
            kS[row][16] = 1.f;  kS[row][17] = 1.f;  kS[row][18] = 0.f;
            kT[row][16] = 0.5f; kT[row][17] = 1.f;  kT[row][18] = 0.f;
        }
        // stage V^T: Vs[f][n] from v [.., n, f]
#pragma unroll
        for (int i = 0; i < 2; ++i) {
            const int lin = i * 256 + t;
            const int nl = lin >> 3, f8 = (lin & 7) * 8;
            uint4 vv = *(const uint4*)(Vh + (size_t)(n0 + nl) * 64 + f8);
            const u16* ve = (const u16*)&vv;
#pragma unroll
            for (int e = 0; e < 8; ++e) Vs[f8 + e][nl] = ve[e];
        }
        __syncthreads();
        // compute KF rows (transposed layout [dd][n]), bf16, packed u32 writes
        {
            unsigned int* dst = (unsigned int*)&KFs[t][0];
#pragma unroll 8
            for (int i = 0; i < 32; ++i) {
                const float v0 = kS[2 * i][i2a]     * kT[2 * i][j2a];
                const float v1 = kS[2 * i + 1][i2a] * kT[2 * i + 1][j2a];
                dst[i] = (unsigned int)f2bf(v0) | ((unsigned int)f2bf(v1) << 16);
            }
            if (t < 32) {
                unsigned int* dst2 = (unsigned int*)&KFs[256 + t][0];
#pragma unroll 8
                for (int i = 0; i < 32; ++i) {
                    const float v0 = kS[2 * i][i2b]     * kT[2 * i][j2b];
                    const float v1 = kS[2 * i + 1][i2b] * kT[2 * i + 1][j2b];
                    dst2[i] = (unsigned int)f2bf(v0) | ((unsigned int)f2bf(v1) << 16);
                }
            }
        }
        __syncthreads();
        // MFMA: C[f, dd] += Vs-rows . KFs-rows^T
#pragma unroll
        for (int kt = 0; kt < 2; ++kt) {
            s16x8 va[4];
#pragma unroll
            for (int mt = 0; mt < 4; ++mt)
                va[mt] = *(const s16x8*)&Vs[mt * 16 + c][kt * 32 + qd * 8];
#pragma unroll
            for (int j = 0; j < 5; ++j) {
                const int dt = w + 4 * j;
                if (dt < 18) {
                    s16x8 vb = *(const s16x8*)&KFs[dt * 16 + c][kt * 32 + qd * 8];
#pragma unroll
                    for (int mt = 0; mt < 4; ++mt)
                        acc[mt][j] = __builtin_amdgcn_mfma_f32_16x16x32_bf16(va[mt], vb, acc[mt][j], 0, 0, 0);
                }
            }
        }
    }

    // store partial [ns][bh][f][273]
    float* base = kvpart + ((size_t)(ns * 64 + bh) * 64) * 273;
#pragma unroll
    for (int j = 0; j < 5; ++j) {
        const int dt = w + 4 * j;
        if (dt >= 18) continue;
        const int dd = dt * 16 + c;
        if (dd >= 273) continue;
#pragma unroll
        for (int mt = 0; mt < 4; ++mt)
#pragma unroll
            for (int r = 0; r < 4; ++r) {
                const int f = mt * 16 + qd * 4 + r;
                base[f * 273 + dd] = acc[mt][j][r];
            }
    }
}

__global__ __launch_bounds__(256)
void kv_fin_kernel(const float* __restrict__ kvpart, float* __restrict__ o)
{
    const int i = blockIdx.x * 256 + threadIdx.x;
    if (i < 64 * 64 * 273) o[i] = kvpart[i] + kvpart[i + 64 * 64 * 273];
}

// ---------------------------------------------------------------------------
extern "C" void kernel_launch(void* const* d_in, const int* in_sizes, int n_in,
                              void* d_out, int out_size, void* d_ws, size_t ws_size,
                              hipStream_t stream)
{
    const void* H  = d_in[0];
    const void* Wq = d_in[1];
    const void* Wk = d_in[2];
    const void* Wv = d_in[3];
    const void* Wo = d_in[4];
    const void* gw = d_in[5];
    float* outf = (float*)d_out;

    char* ws = (char*)d_ws;
    const size_t M = 1 << 20;
    u16*   Hb    = (u16*)(ws);                          // 16 MiB (reused as yn)
    u16*   Wqb   = (u16*)(ws + 16 * M);
    u16*   Wkb   = (u16*)(ws + 16 * M + 512 * 1024);
    u16*   Wvb   = (u16*)(ws + 17 * M);
    u16*   Wob   = (u16*)(ws + 19 * M);
    u16*   gwb   = (u16*)(ws + 21 * M);
    int*   flag  = (int*)(ws + 21 * M + 4096);
    u16*   q     = (u16*)(ws + 22 * M);                 // 4 MiB
    u16*   k     = (u16*)(ws + 26 * M);                 // 4 MiB
    u16*   v     = (u16*)(ws + 30 * M);                 // 16 MiB [b,h,l,64]
    u16*   y     = (u16*)(ws + 46 * M);                 // 16 MiB [b,h,l,64]
    float* kvpart= (float*)(ws + 62 * M);               // 2 x 4.26 MiB partials
    u16*   yn    = Hb;                                  // reuse after gemm0

    detect_kernel<<<1, 64, 0, stream>>>((const unsigned int*)H, flag);
    cvt_kernel<<<(in_sizes[0] + 255) / 256, 256, 0, stream>>>(H,  Hb,  in_sizes[0], flag);
    cvt_kernel<<<(in_sizes[1] + 255) / 256, 256, 0, stream>>>(Wq, Wqb, in_sizes[1], flag);
    cvt_kernel<<<(in_sizes[2] + 255) / 256, 256, 0, stream>>>(Wk, Wkb, in_sizes[2], flag);
    cvt_kernel<<<(in_sizes[3] + 255) / 256, 256, 0, stream>>>(Wv, Wvb, in_sizes[3], flag);
    cvt_kernel<<<(in_sizes[4] + 255) / 256, 256, 0, stream>>>(Wo, Wob, in_sizes[4], flag);
    cvt_kernel<<<1, 256, 0, stream>>>(gw, gwb, in_sizes[5], flag);

    gemm_nt<0><<<dim3(12, 64), 256, 0, stream>>>(Hb, Wqb, Wkb, Wvb, q, k, v, nullptr);
    attn_kernel<<<dim3(16, 64), 256, 0, stream>>>(q, k, v, y);
    rms_kernel<<<32768, 256, 0, stream>>>(y, gwb, yn);
    kv_mfma_kernel<<<dim3(2, 64), 256, 0, stream>>>(k, v, kvpart);
    kv_fin_kernel<<<4368, 256, 0, stream>>>(kvpart, outf + (size_t)8388608);
    gemm_nt<1><<<dim3(8, 64), 256, 0, stream>>>(yn, Wob, nullptr, nullptr,
                                                nullptr, nullptr, nullptr, outf);
}

// Round 7
// 354.901 us; speedup vs baseline: 1.5111x; 1.2073x over previous
//
#include <hip/hip_runtime.h>

// ---------------------------------------------------------------------------
// LinearAttention (Taylor feature map), MI355X/gfx950.
// Inputs: FLOAT32 (runtime-probed; bf16 copies in ws). Outputs: FLOAT32
// [out (4,2048,1024) | kv_state (4,16,1,64,273)].
//
// qf.kf = 1 + (q.k)/4 + (q.k)^2/32 -> attention needs only S=QK^T.
// kv_state is a GEMM: KV[f,dd] = sum_n V^T[f,n] KF[n,dd].
//
// r7: attn rewritten — S^T orientation (A=K rows, B=Q regs), packed b64
// Ps writes, V^T staged from a vt HBM copy (conflict-free b128), per-wave
// private Ps rows (no Ps barrier), 2 half-chunks -> 39.9KB LDS, 4 blocks/CU.
// ---------------------------------------------------------------------------

typedef unsigned short u16;
typedef __attribute__((ext_vector_type(4))) float f32x4;
typedef __attribute__((ext_vector_type(8))) short s16x8;

__device__ __forceinline__ float bf2f(u16 u) {
    union { unsigned int i; float f; } x; x.i = ((unsigned int)u) << 16; return x.f;
}
__device__ __forceinline__ u16 f2bf(float f) {
    union { float f; unsigned int u; } x; x.f = f;
    unsigned int r = x.u + 0x7FFFu + ((x.u >> 16) & 1u);
    return (u16)(r >> 16);
}

// ---------------- input dtype probe + convert -------------------------------
__global__ void detect_kernel(const unsigned int* __restrict__ H, int* __restrict__ flag)
{
    const int lane = threadIdx.x;
    int cnt = 0;
#pragma unroll
    for (int i = 0; i < 16; ++i) {
        const unsigned int wrd = H[lane * 16 + i];
        const int e = (int)((wrd >> 7) & 0xFFu);
        if (e >= 85 && e <= 170) ++cnt;
    }
    cnt += __shfl_xor(cnt, 1);  cnt += __shfl_xor(cnt, 2);
    cnt += __shfl_xor(cnt, 4);  cnt += __shfl_xor(cnt, 8);
    cnt += __shfl_xor(cnt, 16); cnt += __shfl_xor(cnt, 32);
    if (lane == 0) *flag = (cnt < 700) ? 1 : 0;    // 1 = inputs are f32
}

__global__ __launch_bounds__(256)
void cvt_kernel(const void* __restrict__ src, u16* __restrict__ dst, int n,
                const int* __restrict__ flag)
{
    const int i = blockIdx.x * 256 + threadIdx.x;
    if (i >= n) return;
    if (*flag) dst[i] = f2bf(((const float*)src)[i]);
    else       dst[i] = ((const u16*)src)[i];
}

// ---------------- GEMM: C = A(8192,1024) . B(N,1024)^T, bf16 in, f32 acc ----
// MODE 0: fused QKV (N=1536): q,k head-interleaved bf16; V -> vt [b,h,64,l].
// MODE 1: N=1024, FLOAT32 row-major output Of.
template<int MODE>
__global__ __launch_bounds__(256)
void gemm_nt(const u16* __restrict__ A,
             const u16* __restrict__ Bq, const u16* __restrict__ Bk,
             const u16* __restrict__ Bv,
             u16* __restrict__ Oq, u16* __restrict__ Ok,
             u16* __restrict__ Ovt, float* __restrict__ Of)
{
    __shared__ __attribute__((aligned(16))) u16 As[128][40];
    __shared__ __attribute__((aligned(16))) u16 Bs[128][40];
    const int t = threadIdx.x;
    const int lane = t & 63, w = t >> 6;
    const int c = lane & 15, qd = lane >> 4;
    const int wm = (w >> 1) * 64, wn = (w & 1) * 64;
    const int rm = blockIdx.y * 128;
    const int cb = blockIdx.x * 128;

    const u16* Bsrc; int wrow0;
    if (MODE == 0) {
        if (cb < 256)      { Bsrc = Bq; wrow0 = cb; }
        else if (cb < 512) { Bsrc = Bk; wrow0 = cb - 256; }
        else               { Bsrc = Bv; wrow0 = cb - 512; }
    } else { Bsrc = Bq; wrow0 = cb; }

    f32x4 acc[4][4];
#pragma unroll
    for (int i = 0; i < 4; ++i)
#pragma unroll
        for (int j = 0; j < 4; ++j) acc[i][j] = (f32x4){0.f, 0.f, 0.f, 0.f};

    const int r0 = t >> 2, s0 = t & 3;
    const u16* Ap = A    + (size_t)(rm    + r0) * 1024 + s0 * 8;
    const u16* Bp = Bsrc + (size_t)(wrow0 + r0) * 1024 + s0 * 8;

    for (int kt = 0; kt < 32; ++kt) {
        const int k0 = kt * 32;
        uint4 a0 = *(const uint4*)(Ap + k0);
        uint4 a1 = *(const uint4*)(Ap + 64 * 1024 + k0);
        uint4 b0 = *(const uint4*)(Bp + k0);
        uint4 b1 = *(const uint4*)(Bp + 64 * 1024 + k0);
        __syncthreads();
        *(uint4*)&As[r0][s0 * 8]      = a0;
        *(uint4*)&As[r0 + 64][s0 * 8] = a1;
        *(uint4*)&Bs[r0][s0 * 8]      = b0;
        *(uint4*)&Bs[r0 + 64][s0 * 8] = b1;
        __syncthreads();
        s16x8 af[4], bfr[4];
#pragma unroll
        for (int mt = 0; mt < 4; ++mt) af[mt]  = *(const s16x8*)&As[wm + mt * 16 + c][qd * 8];
#pragma unroll
        for (int nt = 0; nt < 4; ++nt) bfr[nt] = *(const s16x8*)&Bs[wn + nt * 16 + c][qd * 8];
#pragma unroll
        for (int mt = 0; mt < 4; ++mt)
#pragma unroll
            for (int nt = 0; nt < 4; ++nt)
                acc[mt][nt] = __builtin_amdgcn_mfma_f32_16x16x32_bf16(af[mt], bfr[nt], acc[mt][nt], 0, 0, 0);
    }

#pragma unroll
    for (int mt = 0; mt < 4; ++mt) {
#pragma unroll
        for (int nt = 0; nt < 4; ++nt) {
            const int gc = cb + wn + nt * 16 + c;
            const int row0 = rm + wm + mt * 16 + qd * 4;
            if (MODE == 1) {
#pragma unroll
                for (int r = 0; r < 4; ++r)
                    Of[(size_t)(row0 + r) * 1024 + gc] = acc[mt][nt][r];
            } else if (gc < 512) {
#pragma unroll
                for (int r = 0; r < 4; ++r) {
                    const int row = row0 + r;
                    const int b_ = row >> 11, l_ = row & 2047;
                    const int cc = gc & 255;
                    const int h = cc >> 4, idx = cc & 15;
                    u16* dst = (gc < 256) ? Oq : Ok;
                    dst[(size_t)((b_ * 16 + h) * 2048 + l_) * 16 + idx] = f2bf(acc[mt][nt][r]);
                }
            } else {
                // V -> vt [b,h,64,l], r-consecutive => packed b64 store
                const int cc = gc - 512;
                const int h = cc >> 6, idx = cc & 63;
                const int b_ = row0 >> 11, l0 = row0 & 2047;
                ushort4 pk;
                pk.x = f2bf(acc[mt][nt][0]);
                pk.y = f2bf(acc[mt][nt][1]);
                pk.z = f2bf(acc[mt][nt][2]);
                pk.w = f2bf(acc[mt][nt][3]);
                *(ushort4*)(Ovt + ((size_t)((b_ * 16 + h) * 64 + idx)) * 2048 + l0) = pk;
            }
        }
    }
}

// ---------------- causal phi-attention, UNNORMALIZED y ----------------------
// grid (16, 64); qc = 15 - blockIdx.x (heavy-first). Wave w owns queries
// [w*32, w*32+32): B-frags from global Q (regs, once). Per 128-key chunk:
// stage Ks (b128), Vs=V^T from vt (b128, conflict-free). Two 64-key halves:
// S^T = mfma(K-rows, Q) -> phi -> packed b64 writes into wave-private Ps
// rows -> PV = mfma(Ps-rows, Vs-rows). 2 barriers/chunk. LDS 39.9 KB.
__global__ __launch_bounds__(256, 4)
void attn_kernel(const u16* __restrict__ Qg, const u16* __restrict__ Kg,
                 const u16* __restrict__ Vt, u16* __restrict__ Yg)
{
    __shared__ __attribute__((aligned(16))) u16 Ks[128][16];
    __shared__ __attribute__((aligned(16))) u16 Vs[64][136];
    __shared__ __attribute__((aligned(16))) u16 Ps[128][72];
    const int t = threadIdx.x, lane = t & 63, w = t >> 6;
    const int c = lane & 15, qd = lane >> 4;
    const int bh = blockIdx.y;
    const int qc = 15 - blockIdx.x;
    const int q0 = qc * 128;
    const u16* Qh = Qg + (size_t)bh * (2048 * 16);
    const u16* Kh = Kg + (size_t)bh * (2048 * 16);
    const u16* Vh = Vt + (size_t)bh * (64 * 2048);

    // Q fragments (B-operand), loaded once from global; qd>=2 lanes zero.
    s16x8 bq[2];
#pragma unroll
    for (int mt = 0; mt < 2; ++mt) {
        s16x8 tmp = {0,0,0,0,0,0,0,0};
        if (qd < 2)
            tmp = *(const s16x8*)(Qh + (size_t)(q0 + w * 32 + mt * 16 + c) * 16 + qd * 8);
        bq[mt] = tmp;
    }

    f32x4 yt[2][4];
#pragma unroll
    for (int mt = 0; mt < 2; ++mt)
#pragma unroll
        for (int ft = 0; ft < 4; ++ft) yt[mt][ft] = (f32x4){0.f,0.f,0.f,0.f};
    const f32x4 zacc = {0.f, 0.f, 0.f, 0.f};

    const int qloc0 = w * 32;   // wave's private Ps row base

    for (int kc = 0; kc <= qc; ++kc) {
        const int n0 = kc * 128;
        __syncthreads();                      // prior readers of Ks/Vs done
        {   // stage K chunk [128,16]
            const int row = t >> 1, hf = t & 1;
            *(uint4*)&Ks[row][hf * 8] =
                *(const uint4*)(Kh + (size_t)(n0 + row) * 16 + hf * 8);
        }
#pragma unroll
        for (int i = 0; i < 4; ++i) {         // stage V^T chunk [64,128] from vt
            const int lin = i * 256 + t;
            const int f = lin >> 4, seg = lin & 15;
            *(uint4*)&Vs[f][seg * 8] =
                *(const uint4*)(Vh + (size_t)f * 2048 + n0 + seg * 8);
        }
        __syncthreads();
        const bool diag = (kc == qc);

#pragma unroll
        for (int h = 0; h < 2; ++h) {
            const int k0 = h * 64;
            if (diag && (qloc0 + 31) < k0) break;   // fully masked half

            // S^T: A = K rows (keys), B = Q regs -> C[key][query]
            f32x4 s[4][2];
#pragma unroll
            for (int at = 0; at < 4; ++at) {
                s16x8 ka = {0,0,0,0,0,0,0,0};
                if (qd < 2) ka = *(const s16x8*)&Ks[k0 + at * 16 + c][qd * 8];
#pragma unroll
                for (int mt = 0; mt < 2; ++mt)
                    s[at][mt] = __builtin_amdgcn_mfma_f32_16x16x32_bf16(ka, bq[mt], zacc, 0, 0, 0);
            }
            // phi + causal mask + packed b64 write into wave-private Ps rows
#pragma unroll
            for (int at = 0; at < 4; ++at)
#pragma unroll
                for (int mt = 0; mt < 2; ++mt) {
                    const int qloc = qloc0 + mt * 16 + c;
                    const int kb = k0 + at * 16 + qd * 4;
                    float p[4];
#pragma unroll
                    for (int r = 0; r < 4; ++r) {
                        const float sv = s[at][mt][r];
                        float pv = 1.f + 0.25f * sv + 0.03125f * sv * sv;
                        if (diag && (kb + r) > qloc) pv = 0.f;
                        p[r] = pv;
                    }
                    uint2 pk;
                    pk.x = (unsigned int)f2bf(p[0]) | ((unsigned int)f2bf(p[1]) << 16);
                    pk.y = (unsigned int)f2bf(p[2]) | ((unsigned int)f2bf(p[3]) << 16);
                    *(uint2*)&Ps[qloc][at * 16 + qd * 4] = pk;
                }
            // PV: y[q][f] += P . V  (A = own Ps rows, B = Vs rows) — no barrier
#pragma unroll
            for (int kt = 0; kt < 2; ++kt) {
                s16x8 pa[2], vb[4];
#pragma unroll
                for (int mt = 0; mt < 2; ++mt)
                    pa[mt] = *(const s16x8*)&Ps[qloc0 + mt * 16 + c][kt * 32 + qd * 8];
#pragma unroll
                for (int ft = 0; ft < 4; ++ft)
                    vb[ft] = *(const s16x8*)&Vs[ft * 16 + c][k0 + kt * 32 + qd * 8];
#pragma unroll
                for (int mt = 0; mt < 2; ++mt)
#pragma unroll
                    for (int ft = 0; ft < 4; ++ft)
                        yt[mt][ft] = __builtin_amdgcn_mfma_f32_16x16x32_bf16(pa[mt], vb[ft], yt[mt][ft], 0, 0, 0);
            }
        }
    }

    // store UNNORMALIZED y [b,h,l,64] bf16
#pragma unroll
    for (int mt = 0; mt < 2; ++mt) {
#pragma unroll
        for (int r = 0; r < 4; ++r) {
            const int i = q0 + w * 32 + mt * 16 + qd * 4 + r;
            u16* dst = Yg + ((size_t)bh * 2048 + i) * 64;
#pragma unroll
            for (int ft = 0; ft < 4; ++ft)
                dst[ft * 16 + c] = f2bf(yt[mt][ft][r]);
        }
    }
}

// ---------------- standalone RMSNorm: y [b,h,l,64] -> yn [b,l,1024] ---------
__global__ __launch_bounds__(256)
void rms_kernel(const u16* __restrict__ Yg, const u16* __restrict__ gw,
                u16* __restrict__ Yn)
{
    const int t = threadIdx.x, lane = t & 63, wv = t >> 6;
    const int row = blockIdx.x * 4 + wv;           // row = (b*16+h)*2048 + l
    const float v = bf2f(Yg[(size_t)row * 64 + lane]);
    float ss = v * v;
    ss += __shfl_xor(ss, 1);  ss += __shfl_xor(ss, 2);
    ss += __shfl_xor(ss, 4);  ss += __shfl_xor(ss, 8);
    ss += __shfl_xor(ss, 16); ss += __shfl_xor(ss, 32);
    const float rms = rsqrtf(ss * (1.0f / 64.0f) + 1e-5f);
    const int bh = row >> 11, l = row & 2047;
    const int b_ = bh >> 4, h_ = bh & 15;
    Yn[((size_t)(b_ * 2048 + l)) * 1024 + h_ * 64 + lane] =
        f2bf(v * rms * bf2f(gw[lane]));
}

// ---------------- kv_state as MFMA GEMM -------------------------------------
__global__ __launch_bounds__(256)
void kv_mfma_kernel(const u16* __restrict__ Kg, const u16* __restrict__ Vt,
                    float* __restrict__ kvpart)
{
    __shared__ __attribute__((aligned(16))) float kS[64][20];
    __shared__ __attribute__((aligned(16))) float kT[64][20];
    __shared__ __attribute__((aligned(16))) u16 KFs[288][72];
    __shared__ __attribute__((aligned(16))) u16 Vs[64][72];
    const int t = threadIdx.x, lane = t & 63, w = t >> 6;
    const int c = lane & 15, qd = lane >> 4;
    const int ns = blockIdx.x, bh = blockIdx.y;
    const u16* Kh  = Kg + (size_t)bh * 2048 * 16;
    const u16* Vth = Vt + (size_t)bh * 64 * 2048;

    int i2a, j2a, i2b = 18, j2b = 18;
    {
        const int dd = t;
        if (dd == 0)      { i2a = 16; j2a = 17; }
        else if (dd < 17) { i2a = dd - 1; j2a = 16; }
        else              { i2a = (dd - 17) >> 4; j2a = (dd - 17) & 15; }
        if (t < 32) {
            const int d2 = 256 + t;
            if (d2 < 273) { i2b = (d2 - 17) >> 4; j2b = (d2 - 17) & 15; }
        }
    }

    f32x4 acc[4][5];
#pragma unroll
    for (int mt = 0; mt < 4; ++mt)
#pragma unroll
        for (int j = 0; j < 5; ++j) acc[mt][j] = (f32x4){0.f, 0.f, 0.f, 0.f};

    for (int ch = 0; ch < 16; ++ch) {
        const int n0 = ns * 1024 + ch * 64;
        __syncthreads();
        if (t < 128) {
            const int row = t >> 1, half = t & 1;
            uint4 kv = *(const uint4*)(Kh + (size_t)(n0 + row) * 16 + half * 8);
            const u16* ke = (const u16*)&kv;
#pragma unroll
            for (int e = 0; e < 8; ++e) {
                const float f = bf2f(ke[e]);
                kS[row][half * 8 + e] = f;
                kT[row][half * 8 + e] = f * 0.17677669529663687f;
            }
        } else if (t < 192) {
            const int row = t - 128;
            kS[row][16] = 1.f;  kS[row][17] = 1.f;  kS[row][18] = 0.f;
            kT[row][16] = 0.5f; kT[row][17] = 1.f;  kT[row][18] = 0.f;
        }
        // stage V^T from vt: conflict-free b128
#pragma unroll
        for (int i = 0; i < 2; ++i) {
            const int lin = i * 256 + t;
            const int f = lin >> 3, seg = lin & 7;
            *(uint4*)&Vs[f][seg * 8] =
                *(const uint4*)(Vth + (size_t)f * 2048 + n0 + seg * 8);
        }
        __syncthreads();
        {
            unsigned int* dst = (unsigned int*)&KFs[t][0];
#pragma unroll 8
            for (int i = 0; i < 32; ++i) {
                const float v0 = kS[2 * i][i2a]     * kT[2 * i][j2a];
                const float v1 = kS[2 * i + 1][i2a] * kT[2 * i + 1][j2a];
                dst[i] = (unsigned int)f2bf(v0) | ((unsigned int)f2bf(v1) << 16);
            }
            if (t < 32) {
                unsigned int* dst2 = (unsigned int*)&KFs[256 + t][0];
#pragma unroll 8
                for (int i = 0; i < 32; ++i) {
                    const float v0 = kS[2 * i][i2b]     * kT[2 * i][j2b];
                    const float v1 = kS[2 * i + 1][i2b] * kT[2 * i + 1][j2b];
                    dst2[i] = (unsigned int)f2bf(v0) | ((unsigned int)f2bf(v1) << 16);
                }
            }
        }
        __syncthreads();
#pragma unroll
        for (int kt = 0; kt < 2; ++kt) {
            s16x8 va[4];
#pragma unroll
            for (int mt = 0; mt < 4; ++mt)
                va[mt] = *(const s16x8*)&Vs[mt * 16 + c][kt * 32 + qd * 8];
#pragma unroll
            for (int j = 0; j < 5; ++j) {
                const int dt = w + 4 * j;
                if (dt < 18) {
                    s16x8 vb = *(const s16x8*)&KFs[dt * 16 + c][kt * 32 + qd * 8];
#pragma unroll
                    for (int mt = 0; mt < 4; ++mt)
                        acc[mt][j] = __builtin_amdgcn_mfma_f32_16x16x32_bf16(va[mt], vb, acc[mt][j], 0, 0, 0);
                }
            }
        }
    }

    float* base = kvpart + ((size_t)(ns * 64 + bh) * 64) * 273;
#pragma unroll
    for (int j = 0; j < 5; ++j) {
        const int dt = w + 4 * j;
        if (dt >= 18) continue;
        const int dd = dt * 16 + c;
        if (dd >= 273) continue;
#pragma unroll
        for (int mt = 0; mt < 4; ++mt)
#pragma unroll
            for (int r = 0; r < 4; ++r) {
                const int f = mt * 16 + qd * 4 + r;
                base[f * 273 + dd] = acc[mt][j][r];
            }
    }
}

__global__ __launch_bounds__(256)
void kv_fin_kernel(const float* __restrict__ kvpart, float* __restrict__ o)
{
    const int i = blockIdx.x * 256 + threadIdx.x;
    if (i < 64 * 64 * 273) o[i] = kvpart[i] + kvpart[i + 64 * 64 * 273];
}

// ---------------------------------------------------------------------------
extern "C" void kernel_launch(void* const* d_in, const int* in_sizes, int n_in,
                              void* d_out, int out_size, void* d_ws, size_t ws_size,
                              hipStream_t stream)
{
    const void* H  = d_in[0];
    const void* Wq = d_in[1];
    const void* Wk = d_in[2];
    const void* Wv = d_in[3];
    const void* Wo = d_in[4];
    const void* gw = d_in[5];
    float* outf = (float*)d_out;

    char* ws = (char*)d_ws;
    const size_t M = 1 << 20;
    u16*   Hb    = (u16*)(ws);                          // 16 MiB (reused as yn)
    u16*   Wqb   = (u16*)(ws + 16 * M);
    u16*   Wkb   = (u16*)(ws + 16 * M + 512 * 1024);
    u16*   Wvb   = (u16*)(ws + 17 * M);
    u16*   Wob   = (u16*)(ws + 19 * M);
    u16*   gwb   = (u16*)(ws + 21 * M);
    int*   flag  = (int*)(ws + 21 * M + 4096);
    u16*   q     = (u16*)(ws + 22 * M);                 // 4 MiB
    u16*   k     = (u16*)(ws + 26 * M);                 // 4 MiB
    u16*   vt    = (u16*)(ws + 30 * M);                 // 16 MiB [b,h,64,l]
    u16*   y     = (u16*)(ws + 46 * M);                 // 16 MiB [b,h,l,64]
    float* kvpart= (float*)(ws + 62 * M);               // 2 x 4.26 MiB
    u16*   yn    = Hb;                                  // reuse after gemm0

    detect_kernel<<<1, 64, 0, stream>>>((const unsigned int*)H, flag);
    cvt_kernel<<<(in_sizes[0] + 255) / 256, 256, 0, stream>>>(H,  Hb,  in_sizes[0], flag);
    cvt_kernel<<<(in_sizes[1] + 255) / 256, 256, 0, stream>>>(Wq, Wqb, in_sizes[1], flag);
    cvt_kernel<<<(in_sizes[2] + 255) / 256, 256, 0, stream>>>(Wk, Wkb, in_sizes[2], flag);
    cvt_kernel<<<(in_sizes[3] + 255) / 256, 256, 0, stream>>>(Wv, Wvb, in_sizes[3], flag);
    cvt_kernel<<<(in_sizes[4] + 255) / 256, 256, 0, stream>>>(Wo, Wob, in_sizes[4], flag);
    cvt_kernel<<<1, 256, 0, stream>>>(gw, gwb, in_sizes[5], flag);

    gemm_nt<0><<<dim3(12, 64), 256, 0, stream>>>(Hb, Wqb, Wkb, Wvb, q, k, vt, nullptr);
    attn_kernel<<<dim3(16, 64), 256, 0, stream>>>(q, k, vt, y);
    rms_kernel<<<32768, 256, 0, stream>>>(y, gwb, yn);
    kv_mfma_kernel<<<dim3(2, 64), 256, 0, stream>>>(k, vt, kvpart);
    kv_fin_kernel<<<4368, 256, 0, stream>>>(kvpart, outf + (size_t)8388608);
    gemm_nt<1><<<dim3(8, 64), 256, 0, stream>>>(yn, Wob, nullptr, nullptr,
                                                nullptr, nullptr, nullptr, outf);
}